// Round 5
// baseline (535.295 us; speedup 1.0000x reference)
//
#include <hip/hip_runtime.h>

constexpr int kL = 2, kB = 2, kS = 128, kE = 512, kH = 8, kF = 2048;
constexpr float kScale = 0.125f; // D^-0.5, D=64

typedef __attribute__((ext_vector_type(8))) short s16x8;
typedef __attribute__((ext_vector_type(8))) _Float16 f16x8;
typedef __attribute__((ext_vector_type(4))) float f32x4;

__device__ __forceinline__ unsigned short f2h(float f) {
  union { _Float16 h; unsigned short u; } v;
  v.h = (_Float16)f;  // v_cvt_f16_f32, RNE
  return v.u;
}

__device__ __forceinline__ f32x4 mfma16(s16x8 a, s16x8 b, f32x4 c) {
  return __builtin_amdgcn_mfma_f32_16x16x32_f16(
      __builtin_bit_cast(f16x8, a), __builtin_bit_cast(f16x8, b), c, 0, 0, 0);
}

// ---------------- fp32 -> fp16 cast, 4 elems/thread ----------------
__global__ __launch_bounds__(256) void cast4_kernel(const float4* __restrict__ in,
                                                    unsigned short* __restrict__ out, int n4) {
  int i = blockIdx.x * 256 + threadIdx.x;
  if (i >= n4) return;
  float4 v = in[i];
  union { unsigned short u[4]; unsigned long long ll; } o;
  o.u[0] = f2h(v.x); o.u[1] = f2h(v.y); o.u[2] = f2h(v.z); o.u[3] = f2h(v.w);
  *(unsigned long long*)(out + (size_t)i * 4) = o.ll;
}

__global__ __launch_bounds__(256) void initx_kernel(const float* __restrict__ xin,
                                                    float* __restrict__ curf,
                                                    unsigned short* __restrict__ curb) {
  int i = blockIdx.x * 256 + threadIdx.x;
  float v = xin[i];
  curf[i] = v;
  curb[i] = f2h(v);
}

// ---------------- weight transpose + fp16 cast (batched descs) --------------
struct TDesc { const float* in; unsigned short* out; int K, N, tiles; };
struct TArgs { TDesc d[6]; int n; };

__global__ __launch_bounds__(256) void transpose_pack_kernel(TArgs ta) {
  int bid = blockIdx.x;
  int di = 0;
  while (di < ta.n && bid >= ta.d[di].tiles) { bid -= ta.d[di].tiles; ++di; }
  if (di >= ta.n) return;
  const float* in = ta.d[di].in;
  unsigned short* out = ta.d[di].out;
  int K = ta.d[di].K, N = ta.d[di].N;
  int tn = N >> 5;
  int n0 = (bid % tn) << 5, k0 = (bid / tn) << 5;
  __shared__ float lt[32][33];
  int tx = threadIdx.x & 31, ty = threadIdx.x >> 5;
#pragma unroll
  for (int r = 0; r < 4; ++r) {
    int kk = ty + r * 8;
    lt[kk][tx] = in[(size_t)(k0 + kk) * N + n0 + tx];
  }
  __syncthreads();
#pragma unroll
  for (int r = 0; r < 4; ++r) {
    int nn = ty + r * 8;
    out[(size_t)(n0 + nn) * K + k0 + tx] = f2h(lt[tx][nn]);
  }
}

// ---------------- generic 64x64-tile fp16 MFMA GEMM, C = A @ BT^T ------------
// A: (M x K) fp16 row-major; BT: (N x K) fp16 row-major.
// BTalt: if non-null, tiles with m0 >= 128 use BTalt instead of BT (per-batch
// weight selection for the reference's `attn @ Wo` B==L broadcasting quirk).
// Epilogues: 0: outf=(acc+bias)*scale  1: outf=acc+bias
//            2: outf=acc+bias+resid    3: outb=fp16(gelu(acc+bias))
template <int EPI>
__global__ __launch_bounds__(256) void gemm64(
    const unsigned short* __restrict__ A, const unsigned short* __restrict__ BT,
    const unsigned short* __restrict__ BTalt,
    int N, int K, const float* __restrict__ bias, const float* __restrict__ resid,
    float* __restrict__ outf, unsigned short* __restrict__ outb, float scale) {
  const int m0 = blockIdx.x * 64, n0 = blockIdx.y * 64;
  if (BTalt && m0 >= 128) BT = BTalt;
  const int t = threadIdx.x, lane = t & 63, w = t >> 6;
  const int wm = w >> 1, wn = w & 1;
  const int l15 = lane & 15, l4 = lane >> 4;
  __shared__ __align__(16) short lsA[64 * 72];
  __shared__ __align__(16) short lsB[64 * 72];
  f32x4 acc[2][2] = {};
  for (int k0 = 0; k0 < K; k0 += 64) {
#pragma unroll
    for (int sg = 0; sg < 2; ++sg) {
      int idx = t + sg * 256;
      int row = idx >> 3, cb = (idx & 7) << 3;
      *(s16x8*)&lsA[row * 72 + cb] = *(const s16x8*)&A[(size_t)(m0 + row) * K + k0 + cb];
      *(s16x8*)&lsB[row * 72 + cb] = *(const s16x8*)&BT[(size_t)(n0 + row) * K + k0 + cb];
    }
    __syncthreads();
#pragma unroll
    for (int ks = 0; ks < 2; ++ks) {
      int lk = ks * 32 + l4 * 8;
      s16x8 a[2], bb[2];
#pragma unroll
      for (int mt = 0; mt < 2; ++mt) a[mt] = *(const s16x8*)&lsA[(wm * 32 + mt * 16 + l15) * 72 + lk];
#pragma unroll
      for (int nt = 0; nt < 2; ++nt) bb[nt] = *(const s16x8*)&lsB[(wn * 32 + nt * 16 + l15) * 72 + lk];
#pragma unroll
      for (int mt = 0; mt < 2; ++mt)
#pragma unroll
        for (int nt = 0; nt < 2; ++nt)
          acc[mt][nt] = mfma16(a[mt], bb[nt], acc[mt][nt]);
    }
    __syncthreads();
  }
#pragma unroll
  for (int mt = 0; mt < 2; ++mt) {
#pragma unroll
    for (int nt = 0; nt < 2; ++nt) {
#pragma unroll
      for (int r = 0; r < 4; ++r) {
        int row = m0 + wm * 32 + mt * 16 + l4 * 4 + r;
        int col = n0 + wn * 32 + nt * 16 + l15;
        float val = acc[mt][nt][r] + bias[col];
        size_t idx = (size_t)row * N + col;
        if (EPI == 0) outf[idx] = val * scale;
        else if (EPI == 1) outf[idx] = val;
        else if (EPI == 2) outf[idx] = val + resid[idx];
        else {
          float g = 0.5f * val * (1.0f + erff(val * 0.70710678118654752f));
          outb[idx] = f2h(g);
        }
      }
    }
  }
}

// ---------------- fused relation-GEMM + score reduce -------------------------
// block = (j, b, h): C[i,0:64]=Ua, C[i,64:128]=Ub from rel[b,j,i,:] @ WrT rows,
// then scores[b,h,i,j] = s * sum_d (q'[b,i,h,d]+Ua)(k[b,j,h,d]+Ub)
__global__ __launch_bounds__(256) void score_kernel(
    const unsigned short* __restrict__ relb, const unsigned short* __restrict__ wrT,
    const float* __restrict__ qf, const float* __restrict__ kf,
    float* __restrict__ sc) {
  const int j = blockIdx.x, b = blockIdx.y, h = blockIdx.z;
  const int t = threadIdx.x, lane = t & 63, w = t >> 6;
  const int l15 = lane & 15, l4 = lane >> 4;
  __shared__ __align__(16) short lsA[128 * 72];
  __shared__ __align__(16) short lsB[128 * 72];
  const unsigned short* Ab = relb + ((size_t)b * kS + j) * kS * kE;
  f32x4 acc[2][8] = {};
  for (int k0 = 0; k0 < kE; k0 += 64) {
#pragma unroll
    for (int sg = 0; sg < 4; ++sg) {
      int idx = t + sg * 256;
      int row = idx >> 3, cb = (idx & 7) << 3;
      *(s16x8*)&lsA[row * 72 + cb] = *(const s16x8*)&Ab[(size_t)row * kE + k0 + cb];
      int grow = (row < 64) ? (h * 64 + row) : (kE + h * 64 + row - 64);
      *(s16x8*)&lsB[row * 72 + cb] = *(const s16x8*)&wrT[(size_t)grow * kE + k0 + cb];
    }
    __syncthreads();
#pragma unroll
    for (int ks = 0; ks < 2; ++ks) {
      int lk = ks * 32 + l4 * 8;
      s16x8 a[2], bb[8];
#pragma unroll
      for (int mt = 0; mt < 2; ++mt) a[mt] = *(const s16x8*)&lsA[(w * 32 + mt * 16 + l15) * 72 + lk];
#pragma unroll
      for (int nt = 0; nt < 8; ++nt) bb[nt] = *(const s16x8*)&lsB[(nt * 16 + l15) * 72 + lk];
#pragma unroll
      for (int mt = 0; mt < 2; ++mt)
#pragma unroll
        for (int nt = 0; nt < 8; ++nt)
          acc[mt][nt] = mfma16(a[mt], bb[nt], acc[mt][nt]);
    }
    __syncthreads();
  }
  const float* krow = kf + ((size_t)b * kS + j) * kE + h * 64;
  float kv[4];
#pragma unroll
  for (int nt = 0; nt < 4; ++nt) kv[nt] = krow[nt * 16 + l15];
#pragma unroll
  for (int mt = 0; mt < 2; ++mt) {
#pragma unroll
    for (int r = 0; r < 4; ++r) {
      int i = w * 32 + mt * 16 + l4 * 4 + r;
      const float* qrow = qf + ((size_t)b * kS + i) * kE + h * 64;
      float p = 0.f;
#pragma unroll
      for (int nt = 0; nt < 4; ++nt) {
        float qv = qrow[nt * 16 + l15];
        p += (qv + acc[mt][nt][r]) * (kv[nt] + acc[mt][nt + 4][r]);
      }
#pragma unroll
      for (int o = 1; o < 16; o <<= 1) p += __shfl_xor(p, o, 16);
      if (l15 == 0) sc[(((size_t)b * kH + h) * kS + i) * kS + j] = kScale * p;
    }
  }
}

// ---------------- softmax over j (rows of length S=128) ----------------------
__global__ __launch_bounds__(128) void softmax_kernel(float* __restrict__ sc) {
  float* p = sc + (size_t)blockIdx.x * kS;
  int t = threadIdx.x, lane = t & 63, w = t >> 6;
  float v = p[t];
  float m = v;
#pragma unroll
  for (int o = 32; o; o >>= 1) m = fmaxf(m, __shfl_xor(m, o));
  __shared__ float r1[2], r2[2];
  if (lane == 0) r1[w] = m;
  __syncthreads();
  m = fmaxf(r1[0], r1[1]);
  float e = expf(v - m);
  float s = e;
#pragma unroll
  for (int o = 32; o; o >>= 1) s += __shfl_xor(s, o);
  if (lane == 0) r2[w] = s;
  __syncthreads();
  s = r2[0] + r2[1];
  p[t] = e / s;
}

// ---------------- attn = w @ v  ->  fp16 (B,S,E) -----------------------------
__global__ __launch_bounds__(256) void attn_v_kernel(
    const float* __restrict__ wsc, const float* __restrict__ vf,
    unsigned short* __restrict__ attnb) {
  const int i = blockIdx.x, b = blockIdx.y, t = threadIdx.x;
  __shared__ float lw[kH][kS];
#pragma unroll
  for (int sg = 0; sg < 4; ++sg) {
    int idx = t + sg * 256;
    int hh = idx >> 7, jj = idx & 127;
    lw[hh][jj] = wsc[(((size_t)b * kH + hh) * kS + i) * kS + jj];
  }
  __syncthreads();
  const float* vb = vf + (size_t)b * kS * kE;
  int h0 = t >> 6;
  float s0 = 0.f, s1 = 0.f;
  for (int jj = 0; jj < kS; ++jj) {
    s0 += lw[h0][jj] * vb[(size_t)jj * kE + t];
    s1 += lw[h0 + 4][jj] * vb[(size_t)jj * kE + t + 256];
  }
  size_t o = ((size_t)b * kS + i) * kE;
  attnb[o + t] = f2h(s0);
  attnb[o + t + 256] = f2h(s1);
}

// ---------------- LayerNorm over E=512, writes fp32 + fp16 -------------------
__global__ __launch_bounds__(256) void ln_kernel(
    const float* __restrict__ in, const float* __restrict__ g, const float* __restrict__ bb,
    float* __restrict__ outf, unsigned short* __restrict__ outb) {
  int row = blockIdx.x, t = threadIdx.x, lane = t & 63, w = t >> 6;
  const float* p = in + (size_t)row * kE;
  float v0 = p[t], v1 = p[t + 256];
  float s = v0 + v1, q = v0 * v0 + v1 * v1;
#pragma unroll
  for (int o = 32; o; o >>= 1) { s += __shfl_xor(s, o); q += __shfl_xor(q, o); }
  __shared__ float rs[4], rq[4];
  if (lane == 0) { rs[w] = s; rq[w] = q; }
  __syncthreads();
  s = rs[0] + rs[1] + rs[2] + rs[3];
  q = rq[0] + rq[1] + rq[2] + rq[3];
  float mu = s * (1.0f / kE);
  float var = q * (1.0f / kE) - mu * mu;
  float inv = rsqrtf(var + 1e-5f);
  float o0 = (v0 - mu) * inv * g[t] + bb[t];
  float o1 = (v1 - mu) * inv * g[t + 256] + bb[t + 256];
  size_t base = (size_t)row * kE;
  outf[base + t] = o0; outf[base + t + 256] = o1;
  outb[base + t] = f2h(o0); outb[base + t + 256] = f2h(o1);
}

extern "C" void kernel_launch(void* const* d_in, const int* in_sizes, int n_in,
                              void* d_out, int out_size, void* d_ws, size_t ws_size,
                              hipStream_t stream) {
  (void)in_sizes; (void)n_in; (void)out_size; (void)ws_size;
  const float* x_in = (const float*)d_in[0];
  const float* rel  = (const float*)d_in[1];
  const float* Wq = (const float*)d_in[2];
  const float* bq = (const float*)d_in[3];
  const float* Wk = (const float*)d_in[4];
  const float* bk = (const float*)d_in[5];
  const float* Wv = (const float*)d_in[6];
  const float* bv = (const float*)d_in[7];
  const float* Wr = (const float*)d_in[8];
  const float* Wo = (const float*)d_in[9];
  const float* bo = (const float*)d_in[10];
  const float* W1 = (const float*)d_in[11];
  const float* b1 = (const float*)d_in[12];
  const float* W2 = (const float*)d_in[13];
  const float* b2 = (const float*)d_in[14];
  const float* ln1g = (const float*)d_in[15];
  const float* ln1b = (const float*)d_in[16];
  const float* ln2g = (const float*)d_in[17];
  const float* ln2b = (const float*)d_in[18];

  char* ws = (char*)d_ws;
  size_t off = 0;
  auto alloc = [&](size_t bytes) -> char* {
    char* p = ws + off;
    off += (bytes + 255) & ~(size_t)255;
    return p;
  };

  unsigned short* relb = (unsigned short*)alloc((size_t)kB * kS * kS * kE * 2);
  float* scores = (float*)alloc((size_t)kB * kH * kS * kS * 4);
  float* qf = (float*)alloc((size_t)kB * kS * kE * 4);
  float* kf = (float*)alloc((size_t)kB * kS * kE * 4);
  float* vf = (float*)alloc((size_t)kB * kS * kE * 4);
  float* curf = (float*)alloc((size_t)kB * kS * kE * 4);
  unsigned short* curb = (unsigned short*)alloc((size_t)kB * kS * kE * 2);
  float* tmp = (float*)alloc((size_t)kB * kS * kE * 4);
  unsigned short* h1b = (unsigned short*)alloc((size_t)kB * kS * kF * 2);
  unsigned short* attnb = (unsigned short*)alloc((size_t)kB * kS * kE * 2);
  unsigned short* wqT = (unsigned short*)alloc((size_t)kE * kE * 2);
  unsigned short* wkT = (unsigned short*)alloc((size_t)kE * kE * 2);
  unsigned short* wvT = (unsigned short*)alloc((size_t)kE * kE * 2);
  unsigned short* wrT = (unsigned short*)alloc((size_t)2 * kE * kE * 2);
  unsigned short* woT0 = (unsigned short*)alloc((size_t)kE * kE * 2);  // Wo[0] — batch 0
  unsigned short* woT1 = (unsigned short*)alloc((size_t)kE * kE * 2);  // Wo[1] — batch 1
  unsigned short* w1T = (unsigned short*)alloc((size_t)kF * kE * 2);
  unsigned short* w2T = (unsigned short*)alloc((size_t)kE * kF * 2);

  int n4 = kB * kS * kS * kE / 4;
  cast4_kernel<<<(n4 + 255) / 256, 256, 0, stream>>>((const float4*)rel, relb, n4);
  initx_kernel<<<kB * kS * kE / 256, 256, 0, stream>>>(x_in, curf, curb);

  // Wo is NOT layer-indexed in the reference: `attn @ Wo` broadcasts the
  // (L,E,E) tensor against (B,S,E) with B==L, i.e. batch b uses Wo[b] in
  // BOTH layers. Pack both once, outside the layer loop.
  {
    TArgs tw;
    tw.n = 2;
    tw.d[0] = { Wo, woT0, kE, kE, (kE / 32) * (kE / 32) };
    tw.d[1] = { Wo + (size_t)kE * kE, woT1, kE, kE, (kE / 32) * (kE / 32) };
    transpose_pack_kernel<<<2 * (kE / 32) * (kE / 32), 256, 0, stream>>>(tw);
  }

  for (int l = 0; l < kL; ++l) {
    TArgs ta;
    ta.n = 6;
    ta.d[0] = { Wq + (size_t)l * kE * kE, wqT, kE, kE, (kE / 32) * (kE / 32) };
    ta.d[1] = { Wk + (size_t)l * kE * kE, wkT, kE, kE, (kE / 32) * (kE / 32) };
    ta.d[2] = { Wv + (size_t)l * kE * kE, wvT, kE, kE, (kE / 32) * (kE / 32) };
    ta.d[3] = { Wr + (size_t)l * kE * 2 * kE, wrT, kE, 2 * kE, (kE / 32) * (2 * kE / 32) };
    ta.d[4] = { W1 + (size_t)l * kE * kF, w1T, kE, kF, (kE / 32) * (kF / 32) };
    ta.d[5] = { W2 + (size_t)l * kF * kE, w2T, kF, kE, (kF / 32) * (kE / 32) };
    int total_tiles = 0;
    for (int i = 0; i < 6; ++i) total_tiles += ta.d[i].tiles;
    transpose_pack_kernel<<<total_tiles, 256, 0, stream>>>(ta);

    gemm64<0><<<dim3(4, kE / 64), 256, 0, stream>>>(curb, wqT, nullptr, kE, kE, bq + (size_t)l * kE, nullptr, qf, nullptr, kScale);
    gemm64<1><<<dim3(4, kE / 64), 256, 0, stream>>>(curb, wkT, nullptr, kE, kE, bk + (size_t)l * kE, nullptr, kf, nullptr, 1.f);
    gemm64<1><<<dim3(4, kE / 64), 256, 0, stream>>>(curb, wvT, nullptr, kE, kE, bv + (size_t)l * kE, nullptr, vf, nullptr, 1.f);

    score_kernel<<<dim3(kS, kB, kH), 256, 0, stream>>>(relb, wrT, qf, kf, scores);
    softmax_kernel<<<kB * kH * kS, 128, 0, stream>>>(scores);
    attn_v_kernel<<<dim3(kS, kB), 256, 0, stream>>>(scores, vf, attnb);

    // per-batch Wo selection: tiles with m0>=128 (batch 1) use woT1
    gemm64<2><<<dim3(4, kE / 64), 256, 0, stream>>>(attnb, woT0, woT1, kE, kE, bo + (size_t)l * kE, curf, tmp, nullptr, 1.f);
    ln_kernel<<<kB * kS, 256, 0, stream>>>(tmp, ln1g + (size_t)l * kE, ln1b + (size_t)l * kE, curf, curb);

    gemm64<3><<<dim3(4, kF / 64), 256, 0, stream>>>(curb, w1T, nullptr, kF, kE, b1 + (size_t)l * kF, nullptr, nullptr, h1b, 1.f);
    gemm64<2><<<dim3(4, kE / 64), 256, 0, stream>>>(h1b, w2T, nullptr, kE, kF, b2 + (size_t)l * kE, curf, tmp, nullptr, 1.f);
    ln_kernel<<<kB * kS, 256, 0, stream>>>(tmp, ln2g + (size_t)l * kE, ln2b + (size_t)l * kE, curf, curb);
  }

  hipMemcpyAsync(d_out, curf, (size_t)kB * kS * kE * 4, hipMemcpyDeviceToDevice, stream);
}